// Round 2
// baseline (2513.044 us; speedup 1.0000x reference)
//
#include <hip/hip_runtime.h>
#include <hip/hip_bf16.h>
#include <cstdint>

// ---------------------------------------------------------------------------
// WorldModel RSSM: B=1024 T=50 E=1024 A=6 S=200 H=200 L=30
// Device buffers are fp32 (reference dtype float32). Internal GEMMs run in
// bf16 MFMA with fp32 accumulation; GI intermediate stored bf16 in workspace.
//
// Decomposition:
//   GI[bt,0:600]  = concat(a,e) @ W_ih + b_ih          (parallel, MFMA GEMM)
//   GI[bt,600:800]= e @ Wq1[200:,:] + bq1  (QE)        (same GEMM, extra cols)
//   sequential scan: 64 blocks x 16 batch rows, block-local recurrence.
// ---------------------------------------------------------------------------

typedef __attribute__((ext_vector_type(8))) short   short8;
typedef __attribute__((ext_vector_type(8))) __bf16  bf16x8;
typedef __attribute__((ext_vector_type(4))) float   f32x4;

__device__ __forceinline__ float bf2f(unsigned short u) {
    unsigned int v = ((unsigned int)u) << 16;
    return __builtin_bit_cast(float, v);
}
__device__ __forceinline__ unsigned short f2bf(float f) {
    unsigned int v = __builtin_bit_cast(unsigned int, f);
    v = v + 0x7FFFu + ((v >> 16) & 1u);   // RNE
    return (unsigned short)(v >> 16);
}
__device__ __forceinline__ float softplusf(float x) {
    return (x > 20.f) ? x : log1pf(__expf(x));
}

// ---------------- workspace layout (bytes) ----------------
// GI    : 51200*800*2 = 81,920,000   (bf16)
// Bpack : 32*50*512*2 =  1,638,400   (k1 B fragments, bf16)
// Whh_p : 7*39*512*2  =    279,552   (gh   B fragments, K pad 224, N 3x208)
// Wpq1  : 7*26*512*2  =    186,368   (heads1: Wp1 | Wq1[:200])
// Wpq2  : 7*8*512*2   =     57,344   (heads2: Wp2 | Wq2, N pad 64)
#define OFF_BPACK 81920000
#define OFF_WHH   83558400
#define OFF_WPQ1  83837952
#define OFF_WPQ2  84024320

// fragment element mapping (mfma_f32_16x16x32_bf16):
//   A[l&15][ (l>>4)*8 + j ],  B[ (l>>4)*8 + j ][ l&15 ],  D[(l>>4)*4 + r][l&15]
// packed B storage: elem = ((kk*NT + nt)*64 + l)*8 + j

__global__ __launch_bounds__(256) void pack_kernel(
    const float* __restrict__ W_ih, const float* __restrict__ W_hh,
    const float* __restrict__ Wp1,  const float* __restrict__ Wq1,
    const float* __restrict__ Wp2,  const float* __restrict__ Wq2,
    unsigned short* __restrict__ Bpack, unsigned short* __restrict__ Whh_p,
    unsigned short* __restrict__ Wpq1,  unsigned short* __restrict__ Wpq2)
{
    int e = blockIdx.x * 256 + threadIdx.x;
    if (e < 819200) {                       // k1: K=1024(embed), N=800
        const int j = e & 7, l = (e >> 3) & 63;
        const int nt = (e >> 9) % 50, kk = e / (512 * 50);
        const int k = kk * 32 + (l >> 4) * 8 + j;
        const int c = nt * 16 + (l & 15);
        Bpack[e] = f2bf((c < 600) ? W_ih[(6 + k) * 600 + c]
                                  : Wq1[(200 + k) * 200 + (c - 600)]);
        return;
    }
    e -= 819200;
    if (e < 139776) {                       // W_hh: K pad 224, N = 3 gates x 13 tiles
        const int j = e & 7, l = (e >> 3) & 63;
        const int nt = (e >> 9) % 39, kk = e / (512 * 39);
        const int k = kk * 32 + (l >> 4) * 8 + j;
        const int g = nt / 13, st = nt % 13;
        const int c = st * 16 + (l & 15);
        Whh_p[e] = (k < 200 && c < 200) ? f2bf(W_hh[k * 600 + g * 200 + c]) : (unsigned short)0;
        return;
    }
    e -= 139776;
    if (e < 93184) {                        // heads1: [Wp1 | Wq1[:200]] K pad 224
        const int j = e & 7, l = (e >> 3) & 63;
        const int nt = (e >> 9) % 26, kk = e / (512 * 26);
        const int k = kk * 32 + (l >> 4) * 8 + j;
        unsigned short v = 0;
        if (nt < 13) { const int c = nt * 16 + (l & 15);        if (k < 200 && c < 200) v = f2bf(Wp1[k * 200 + c]); }
        else         { const int c = (nt - 13) * 16 + (l & 15); if (k < 200 && c < 200) v = f2bf(Wq1[k * 200 + c]); }
        Wpq1[e] = v;
        return;
    }
    e -= 93184;
    if (e < 28672) {                        // heads2: [Wp2 | Wq2] N pad 64 each
        const int j = e & 7, l = (e >> 3) & 63;
        const int nt = (e >> 9) % 8, kk = e / (512 * 8);
        const int k = kk * 32 + (l >> 4) * 8 + j;
        unsigned short v = 0;
        if (nt < 4) { const int c = nt * 16 + (l & 15);       if (k < 200 && c < 60) v = f2bf(Wp2[k * 60 + c]); }
        else        { const int c = (nt - 4) * 16 + (l & 15); if (k < 200 && c < 60) v = f2bf(Wq2[k * 60 + c]); }
        Wpq2[e] = v;
    }
}

// ---------------- kernel 1: GI/QE GEMM  M=51200 N=800 K=1024 ----------------
__global__ __launch_bounds__(256, 1) void k1_gi(
    const float* __restrict__ embed,   // [51200][1024]
    const float* __restrict__ action,  // [51200][6]
    const float* __restrict__ W_ih,    // rows 0..5 = action part
    const float* __restrict__ b_ih,
    const float* __restrict__ bq1,
    const unsigned short* __restrict__ Bpack,
    unsigned short* __restrict__ GI)   // [51200][800] bf16
{
    __shared__ unsigned short Bl[25600];       // one K-tile: 50 ntiles x 64 lanes x 8
    const int tid = threadIdx.x;
    const int w = tid >> 6, l = tid & 63;
    const int lo = l & 15, hi = l >> 4;
    const int row_a = blockIdx.x * 64 + w * 16 + lo;

    f32x4 acc[50];
#pragma unroll
    for (int i = 0; i < 50; ++i) acc[i] = f32x4{0.f, 0.f, 0.f, 0.f};

    for (int kk = 0; kk < 32; ++kk) {
        __syncthreads();
        const unsigned short* src = Bpack + kk * 25600;
#pragma unroll
        for (int i = 0; i < 13; ++i) {
            int c = tid + i * 256;
            if (c < 3200) *(short8*)&Bl[c * 8] = *(const short8*)&src[c * 8];
        }
        __syncthreads();
        // A-fragment: convert fp32 embed -> bf16 in-register
        const float* ap = embed + row_a * 1024 + kk * 32 + hi * 8;
        f32x4 e0 = *(const f32x4*)ap;
        f32x4 e1 = *(const f32x4*)(ap + 4);
        short8 sa;
#pragma unroll
        for (int j = 0; j < 4; ++j) { sa[j] = (short)f2bf(e0[j]); sa[4 + j] = (short)f2bf(e1[j]); }
        bf16x8 a = __builtin_bit_cast(bf16x8, sa);
#pragma unroll
        for (int nt = 0; nt < 50; ++nt) {
            bf16x8 b = __builtin_bit_cast(bf16x8, *(const short8*)&Bl[nt * 512 + l * 8]);
            acc[nt] = __builtin_amdgcn_mfma_f32_16x16x32_bf16(a, b, acc[nt], 0, 0, 0);
        }
    }

    // epilogue: bias + action(K=6) contribution, store bf16
    const int rbase = blockIdx.x * 64 + w * 16 + hi * 4;
    float av[4][6];
#pragma unroll
    for (int r = 0; r < 4; ++r)
#pragma unroll
        for (int k = 0; k < 6; ++k) av[r][k] = action[(rbase + r) * 6 + k];

#pragma unroll
    for (int nt = 0; nt < 50; ++nt) {
        const int col = nt * 16 + lo;
        const float bias = (col < 600) ? b_ih[col] : bq1[col - 600];
        float wa[6];
        if (col < 600) {
#pragma unroll
            for (int k = 0; k < 6; ++k) wa[k] = W_ih[k * 600 + col];
        }
#pragma unroll
        for (int r = 0; r < 4; ++r) {
            float v = acc[nt][r] + bias;
            if (col < 600) {
#pragma unroll
                for (int k = 0; k < 6; ++k) v += av[r][k] * wa[k];
            }
            GI[(rbase + r) * 800 + col] = f2bf(v);
        }
    }
}

// ---------------- kernel 2: sequential scan ----------------
#define HSTR 232   // padded LDS row stride (elems); 232%32=8 -> banks spread

__device__ __forceinline__ bf16x8 frag_from_f32(const float* base, int lo, int koff) {
    const float* p = base + lo * HSTR + koff;
    f32x4 v0 = *(const f32x4*)p;
    f32x4 v1 = *(const f32x4*)(p + 4);
    short8 s;
#pragma unroll
    for (int j = 0; j < 4; ++j) { s[j] = (short)f2bf(v0[j]); s[4 + j] = (short)f2bf(v1[j]); }
    return __builtin_bit_cast(bf16x8, s);
}

__global__ __launch_bounds__(256, 1) void k2_scan(
    const unsigned short* __restrict__ GI,     // [51200][800] bf16
    const unsigned short* __restrict__ Whh_p,
    const unsigned short* __restrict__ Wpq1,
    const unsigned short* __restrict__ Wpq2,
    const float* __restrict__ noise,           // [51200][30] fp32
    const float* __restrict__ b_hh,
    const float* __restrict__ bp1,
    const float* __restrict__ bp2,
    const float* __restrict__ bq2,
    float* __restrict__ out)                   // [51200][350] fp32
{
    __shared__ float          hS [16 * HSTR];  // fp32 h state, K-pad zeroed
    __shared__ unsigned short phS[16 * HSTR];  // bf16 elu(prior h1)
    __shared__ unsigned short qhS[16 * HSTR];  // bf16 elu(post  h1)
    __shared__ float          ost[16 * 128];   // raw pm|ps|qm|qs per row

    const int tid = threadIdx.x;
    const int w = tid >> 6, l = tid & 63;
    const int lo = l & 15, hi = l >> 4;
    const int r0 = blockIdx.x * 16;

    for (int i = tid; i < 16 * HSTR; i += 256) { hS[i] = 0.f; phS[i] = 0; qhS[i] = 0; }
    __syncthreads();

    // wave -> s-tile assignment (13 tiles of 16 over cols 0..207)
    const int st0 = (w == 0) ? 0 : (w == 1) ? 4 : (w == 2) ? 7 : 10;
    const int stn = (w == 0) ? 4 : 3;
    // wave -> heads1 tile assignment (26 tiles: 0..12 prior, 13..25 posterior)
    const int h1s = (w < 2) ? 7 * w : 14 + 6 * (w - 2);
    const int h1n = (w < 2) ? 7 : 6;

    for (int t = 0; t < 50; ++t) {
        // ---- A-fragments of h_old
        bf16x8 hf[7];
#pragma unroll
        for (int kk = 0; kk < 7; ++kk) hf[kk] = frag_from_f32(hS, lo, kk * 32 + hi * 8);

        // ---- gh = h @ W_hh  (3 gates x up-to-4 s-tiles per wave)
        f32x4 acc[3][4];
#pragma unroll
        for (int g = 0; g < 3; ++g)
#pragma unroll
            for (int i = 0; i < 4; ++i) acc[g][i] = f32x4{0.f, 0.f, 0.f, 0.f};
#pragma unroll
        for (int i = 0; i < 4; ++i) if (i < stn) {
            const int st = st0 + i;
#pragma unroll
            for (int g = 0; g < 3; ++g) {
                const int nt = g * 13 + st;
#pragma unroll
                for (int kk = 0; kk < 7; ++kk) {
                    bf16x8 b = __builtin_bit_cast(bf16x8,
                        *(const short8*)&Whh_p[((kk * 39 + nt) * 64 + l) * 8]);
                    acc[g][i] = __builtin_amdgcn_mfma_f32_16x16x32_bf16(hf[kk], b, acc[g][i], 0, 0, 0);
                }
            }
        }

        // ---- gates (read h_old + GI, compute h')
        float hnew[4][4];
#pragma unroll
        for (int i = 0; i < 4; ++i) if (i < stn) {
            const int c = (st0 + i) * 16 + lo;
#pragma unroll
            for (int r = 0; r < 4; ++r) {
                if (c < 200) {
                    const int row = hi * 4 + r;
                    const int gib = ((r0 + row) * 50 + t) * 800;
                    const float gr = bf2f(GI[gib + c])       + acc[0][i][r] + b_hh[c];
                    const float gz = bf2f(GI[gib + 200 + c]) + acc[1][i][r] + b_hh[200 + c];
                    const float hn = acc[2][i][r] + b_hh[400 + c];
                    const float gn = bf2f(GI[gib + 400 + c]);
                    const float rr = 1.f / (1.f + __expf(-gr));
                    const float zz = 1.f / (1.f + __expf(-gz));
                    const float nn = tanhf(gn + rr * hn);
                    hnew[i][r] = (1.f - zz) * nn + zz * hS[row * HSTR + c];
                }
            }
        }
        __syncthreads();                       // B1: all h_old reads done
#pragma unroll
        for (int i = 0; i < 4; ++i) if (i < stn) {
            const int c = (st0 + i) * 16 + lo;
            if (c < 200) {
#pragma unroll
                for (int r = 0; r < 4; ++r) hS[(hi * 4 + r) * HSTR + c] = hnew[i][r];
            }
        }
        __syncthreads();                       // B2: h' visible

        // ---- heads1: [ph1|qh1] = elu(h' @ [Wp1|Wq1_s] + {bp1|QE})
        bf16x8 hg[7];
#pragma unroll
        for (int kk = 0; kk < 7; ++kk) hg[kk] = frag_from_f32(hS, lo, kk * 32 + hi * 8);
        f32x4 a2[7];
#pragma unroll
        for (int i = 0; i < 7; ++i) a2[i] = f32x4{0.f, 0.f, 0.f, 0.f};
#pragma unroll
        for (int i = 0; i < 7; ++i) if (i < h1n) {
            const int nt = h1s + i;
#pragma unroll
            for (int kk = 0; kk < 7; ++kk) {
                bf16x8 b = __builtin_bit_cast(bf16x8,
                    *(const short8*)&Wpq1[((kk * 26 + nt) * 64 + l) * 8]);
                a2[i] = __builtin_amdgcn_mfma_f32_16x16x32_bf16(hg[kk], b, a2[i], 0, 0, 0);
            }
        }
#pragma unroll
        for (int i = 0; i < 7; ++i) if (i < h1n) {
            const int nt = h1s + i;
            const bool isq = (nt >= 13);
            const int c1 = (isq ? (nt - 13) : nt) * 16 + lo;
            if (c1 < 200) {
#pragma unroll
                for (int r = 0; r < 4; ++r) {
                    const int row = hi * 4 + r;
                    float v = a2[i][r];
                    if (isq) v += bf2f(GI[((r0 + row) * 50 + t) * 800 + 600 + c1]);  // QE (incl bq1)
                    else     v += bp1[c1];
                    v = (v > 0.f) ? v : expm1f(v);                                    // ELU
                    const unsigned short hv = f2bf(v);
                    if (isq) qhS[row * HSTR + c1] = hv; else phS[row * HSTR + c1] = hv;
                }
            }
        }
        __syncthreads();                       // B3: h1 activations visible

        // ---- heads2: waves 0,1 -> prior (Wp2), waves 2,3 -> posterior (Wq2)
        const unsigned short* srcS = (w < 2) ? phS : qhS;
        bf16x8 pf[7];
#pragma unroll
        for (int kk = 0; kk < 7; ++kk)
            pf[kk] = __builtin_bit_cast(bf16x8,
                *(const short8*)&srcS[lo * HSTR + kk * 32 + hi * 8]);
        f32x4 a3[2];
        a3[0] = f32x4{0.f, 0.f, 0.f, 0.f};
        a3[1] = f32x4{0.f, 0.f, 0.f, 0.f};
#pragma unroll
        for (int i = 0; i < 2; ++i) {
            const int nt = w * 2 + i;
#pragma unroll
            for (int kk = 0; kk < 7; ++kk) {
                bf16x8 b = __builtin_bit_cast(bf16x8,
                    *(const short8*)&Wpq2[((kk * 8 + nt) * 64 + l) * 8]);
                a3[i] = __builtin_amdgcn_mfma_f32_16x16x32_bf16(pf[kk], b, a3[i], 0, 0, 0);
            }
        }
#pragma unroll
        for (int i = 0; i < 2; ++i) {
            const int nt = w * 2 + i;
            const int cl = (nt & 3) * 16 + lo;
            if (cl < 60) {
                const float bb = (nt < 4) ? bp2[cl] : bq2[cl];
                const int obase = ((nt < 4) ? 0 : 64) + ((cl < 30) ? cl : (32 + cl - 30));
#pragma unroll
                for (int r = 0; r < 4; ++r)
                    ost[(hi * 4 + r) * 128 + obase] = a3[i][r] + bb;
            }
        }
        __syncthreads();                       // B4: ost visible

        // ---- final: softplus / rsample / pack 350 cols, write fp32
        for (int idx = tid; idx < 16 * 350; idx += 256) {
            const int row = idx / 350;
            const int c = idx - row * 350;
            const int bt = (r0 + row) * 50 + t;
            const float* o = &ost[row * 128];
            float v;
            if (c < 200)      v = hS[row * HSTR + c];
            else if (c < 230) {
                const int j = c - 200;
                const float qs = softplusf(o[96 + j]) + 0.1f;
                v = o[64 + j] + qs * noise[bt * 30 + j];
            }
            else if (c < 260) v = o[c - 230];
            else if (c < 290) v = softplusf(o[32 + (c - 260)]) + 0.1f;
            else if (c < 320) v = o[64 + (c - 290)];
            else              v = softplusf(o[96 + (c - 320)]) + 0.1f;
            out[bt * 350 + c] = v;
        }
        // next-iteration B1 protects hS/ost against early overwrite
    }
}

// ---------------------------------------------------------------------------
extern "C" void kernel_launch(void* const* d_in, const int* in_sizes, int n_in,
                              void* d_out, int out_size, void* d_ws, size_t ws_size,
                              hipStream_t stream)
{
    const float* action = (const float*)d_in[0];
    const float* embed  = (const float*)d_in[1];
    const float* noise  = (const float*)d_in[2];
    const float* W_ih   = (const float*)d_in[3];
    const float* W_hh   = (const float*)d_in[4];
    const float* b_ih   = (const float*)d_in[5];
    const float* b_hh   = (const float*)d_in[6];
    const float* Wp1    = (const float*)d_in[7];
    const float* bp1    = (const float*)d_in[8];
    const float* Wp2    = (const float*)d_in[9];
    const float* bp2    = (const float*)d_in[10];
    const float* Wq1    = (const float*)d_in[11];
    const float* bq1    = (const float*)d_in[12];
    const float* Wq2    = (const float*)d_in[13];
    const float* bq2    = (const float*)d_in[14];
    (void)in_sizes; (void)n_in; (void)out_size; (void)ws_size;

    char* ws = (char*)d_ws;
    unsigned short* GI    = (unsigned short*)(ws);
    unsigned short* Bpack = (unsigned short*)(ws + OFF_BPACK);
    unsigned short* Whh_p = (unsigned short*)(ws + OFF_WHH);
    unsigned short* Wpq1  = (unsigned short*)(ws + OFF_WPQ1);
    unsigned short* Wpq2  = (unsigned short*)(ws + OFF_WPQ2);
    float* outp = (float*)d_out;

    pack_kernel<<<4222, 256, 0, stream>>>(W_ih, W_hh, Wp1, Wq1, Wp2, Wq2,
                                          Bpack, Whh_p, Wpq1, Wpq2);
    k1_gi<<<800, 256, 0, stream>>>(embed, action, W_ih, b_ih, bq1, Bpack, GI);
    k2_scan<<<64, 256, 0, stream>>>(GI, Whh_p, Wpq1, Wpq2, noise,
                                    b_hh, bp1, bp2, bq2, outp);
}

// Round 3
// 818.971 us; speedup vs baseline: 3.0685x; 3.0685x over previous
//
#include <hip/hip_runtime.h>
#include <hip/hip_bf16.h>
#include <cstdint>

// ---------------------------------------------------------------------------
// WorldModel RSSM: B=1024 T=50 E=1024 A=6 S=200 H=200 L=30
// fp32 in/out; internal GEMMs bf16 MFMA w/ fp32 accum.
//
//   k1: GI[bt,0:600]=concat(a,e)@W_ih+b_ih ; GI[bt,600:800]=e@Wq1[200:]+bq1
//   k2: GRU-only sequential scan (64 blocks x 13 waves, 16 rows each);
//       writes deter fp32 -> out[:,0:200] and bf16 -> GI[bt,0:200] (reuse).
//   k3: heads (fc_prior/fc_posterior + softplus + rsample) fully parallel.
// ---------------------------------------------------------------------------

typedef __attribute__((ext_vector_type(8))) short   short8;
typedef __attribute__((ext_vector_type(8))) __bf16  bf16x8;
typedef __attribute__((ext_vector_type(4))) float   f32x4;

__device__ __forceinline__ float bf2f(unsigned short u) {
    unsigned int v = ((unsigned int)u) << 16;
    return __builtin_bit_cast(float, v);
}
__device__ __forceinline__ unsigned short f2bf(float f) {
    unsigned int v = __builtin_bit_cast(unsigned int, f);
    v = v + 0x7FFFu + ((v >> 16) & 1u);   // RNE
    return (unsigned short)(v >> 16);
}
__device__ __forceinline__ float softplusf(float x) {
    return (x > 20.f) ? x : log1pf(__expf(x));
}

// ---------------- workspace layout (bytes) ----------------
#define OFF_BPACK 81920000
#define OFF_WHH   83558400
#define OFF_WPQ1  83837952
#define OFF_WPQ2  84024320

// fragment mapping (mfma_f32_16x16x32_bf16):
//   A[l&15][(l>>4)*8+j], B[(l>>4)*8+j][l&15], D[(l>>4)*4+r][l&15]
// packed B storage: elem = ((kk*NT + nt)*64 + l)*8 + j

__global__ __launch_bounds__(256) void pack_kernel(
    const float* __restrict__ W_ih, const float* __restrict__ W_hh,
    const float* __restrict__ Wp1,  const float* __restrict__ Wq1,
    const float* __restrict__ Wp2,  const float* __restrict__ Wq2,
    unsigned short* __restrict__ Bpack, unsigned short* __restrict__ Whh_p,
    unsigned short* __restrict__ Wpq1,  unsigned short* __restrict__ Wpq2)
{
    int e = blockIdx.x * 256 + threadIdx.x;
    if (e < 819200) {                       // k1: K=1024(embed), N=800
        const int j = e & 7, l = (e >> 3) & 63;
        const int nt = (e >> 9) % 50, kk = e / (512 * 50);
        const int k = kk * 32 + (l >> 4) * 8 + j;
        const int c = nt * 16 + (l & 15);
        Bpack[e] = f2bf((c < 600) ? W_ih[(6 + k) * 600 + c]
                                  : Wq1[(200 + k) * 200 + (c - 600)]);
        return;
    }
    e -= 819200;
    if (e < 139776) {                       // W_hh: K pad 224, N = 3 gates x 13 tiles
        const int j = e & 7, l = (e >> 3) & 63;
        const int nt = (e >> 9) % 39, kk = e / (512 * 39);
        const int k = kk * 32 + (l >> 4) * 8 + j;
        const int g = nt / 13, st = nt % 13;
        const int c = st * 16 + (l & 15);
        Whh_p[e] = (k < 200 && c < 200) ? f2bf(W_hh[k * 600 + g * 200 + c]) : (unsigned short)0;
        return;
    }
    e -= 139776;
    if (e < 93184) {                        // heads1: [Wp1 | Wq1[:200]] K pad 224
        const int j = e & 7, l = (e >> 3) & 63;
        const int nt = (e >> 9) % 26, kk = e / (512 * 26);
        const int k = kk * 32 + (l >> 4) * 8 + j;
        unsigned short v = 0;
        if (nt < 13) { const int c = nt * 16 + (l & 15);        if (k < 200 && c < 200) v = f2bf(Wp1[k * 200 + c]); }
        else         { const int c = (nt - 13) * 16 + (l & 15); if (k < 200 && c < 200) v = f2bf(Wq1[k * 200 + c]); }
        Wpq1[e] = v;
        return;
    }
    e -= 93184;
    if (e < 28672) {                        // heads2: [Wp2 | Wq2] N pad 64 each
        const int j = e & 7, l = (e >> 3) & 63;
        const int nt = (e >> 9) % 8, kk = e / (512 * 8);
        const int k = kk * 32 + (l >> 4) * 8 + j;
        unsigned short v = 0;
        if (nt < 4) { const int c = nt * 16 + (l & 15);       if (k < 200 && c < 60) v = f2bf(Wp2[k * 60 + c]); }
        else        { const int c = (nt - 4) * 16 + (l & 15); if (k < 200 && c < 60) v = f2bf(Wq2[k * 60 + c]); }
        Wpq2[e] = v;
    }
}

// ---------------- kernel 1: GI/QE GEMM  M=51200 N=800 K=1024 ----------------
// 512 thr = 8 waves: wave = (mp 0..1, nq 0..3); mp -> 2 M-subtiles, nq -> ~13 N-tiles
__global__ __launch_bounds__(512, 1) void k1_gi(
    const float* __restrict__ embed,   // [51200][1024]
    const float* __restrict__ action,  // [51200][6]
    const float* __restrict__ W_ih,    // rows 0..5 = action part
    const float* __restrict__ b_ih,
    const float* __restrict__ bq1,
    const unsigned short* __restrict__ Bpack,
    unsigned short* __restrict__ GI)   // [51200][800] bf16
{
    __shared__ unsigned short Bl[25600];   // one K-tile: 50 ntiles x 64 lanes x 8
    const int tid = threadIdx.x;
    const int w = tid >> 6, l = tid & 63;
    const int lo = l & 15, hi = l >> 4;
    const int mp = w >> 2, nq = w & 3;
    const int n0 = (nq < 2) ? nq * 13 : 26 + (nq - 2) * 12;
    const int nn = (nq < 2) ? 13 : 12;
    const size_t rowA0 = (size_t)(blockIdx.x * 64 + (2 * mp + 0) * 16 + lo);
    const size_t rowA1 = (size_t)(blockIdx.x * 64 + (2 * mp + 1) * 16 + lo);

    f32x4 acc[2][13];
#pragma unroll
    for (int p = 0; p < 2; ++p)
#pragma unroll
        for (int i = 0; i < 13; ++i) acc[p][i] = f32x4{0.f, 0.f, 0.f, 0.f};

    for (int kk = 0; kk < 32; ++kk) {
        __syncthreads();
        const unsigned short* src = Bpack + kk * 25600;
#pragma unroll
        for (int i = 0; i < 7; ++i) {
            int c = tid + i * 512;
            if (c < 3200) *(short8*)&Bl[c * 8] = *(const short8*)&src[c * 8];
        }
        __syncthreads();
        // A-fragments (fp32 -> bf16 in-register) for both M-subtiles
        bf16x8 a[2];
#pragma unroll
        for (int p = 0; p < 2; ++p) {
            const float* ap = embed + (p ? rowA1 : rowA0) * 1024 + kk * 32 + hi * 8;
            f32x4 e0 = *(const f32x4*)ap;
            f32x4 e1 = *(const f32x4*)(ap + 4);
            short8 sa;
#pragma unroll
            for (int j = 0; j < 4; ++j) { sa[j] = (short)f2bf(e0[j]); sa[4 + j] = (short)f2bf(e1[j]); }
            a[p] = __builtin_bit_cast(bf16x8, sa);
        }
#pragma unroll
        for (int i = 0; i < 13; ++i) if (i < nn) {
            bf16x8 b = __builtin_bit_cast(bf16x8, *(const short8*)&Bl[(n0 + i) * 512 + l * 8]);
            acc[0][i] = __builtin_amdgcn_mfma_f32_16x16x32_bf16(a[0], b, acc[0][i], 0, 0, 0);
            acc[1][i] = __builtin_amdgcn_mfma_f32_16x16x32_bf16(a[1], b, acc[1][i], 0, 0, 0);
        }
    }

    // epilogue: bias + action(K=6) contribution, store bf16
#pragma unroll
    for (int p = 0; p < 2; ++p) {
        const int rbase = blockIdx.x * 64 + (2 * mp + p) * 16 + hi * 4;
        float av[4][6];
#pragma unroll
        for (int r = 0; r < 4; ++r)
#pragma unroll
            for (int k = 0; k < 6; ++k) av[r][k] = action[(size_t)(rbase + r) * 6 + k];
#pragma unroll
        for (int i = 0; i < 13; ++i) if (i < nn) {
            const int col = (n0 + i) * 16 + lo;
            const float bias = (col < 600) ? b_ih[col] : bq1[col - 600];
            float wa[6];
            if (col < 600) {
#pragma unroll
                for (int k = 0; k < 6; ++k) wa[k] = W_ih[k * 600 + col];
            }
#pragma unroll
            for (int r = 0; r < 4; ++r) {
                float v = acc[p][i][r] + bias;
                if (col < 600) {
#pragma unroll
                    for (int k = 0; k < 6; ++k) v += av[r][k] * wa[k];
                }
                GI[(size_t)(rbase + r) * 800 + col] = f2bf(v);
            }
        }
    }
}

// ---------------- kernel 2: GRU-only sequential scan ----------------
// 64 blocks x 832 thr (13 waves). Wave w owns s-tile w (cols w*16..+15), all 3 gates.
// h: bf16 in LDS (MFMA A-operand) + per-thread fp32 h_reg for z*h and output.
#define HSTRB 232   // LDS row stride in bf16 elems (K pad >=224)

__global__ __launch_bounds__(832, 1) void k2_scan(
    unsigned short* __restrict__ GI,           // [51200][800] bf16 (deter written into cols 0..199)
    const unsigned short* __restrict__ Whh_p,
    const float* __restrict__ b_hh,
    float* __restrict__ out)                   // [51200][350] fp32 (cols 0..199 here)
{
    __shared__ unsigned short hS[16 * HSTRB];  // bf16 h, K-pad zeroed

    const int tid = threadIdx.x;
    const int w = tid >> 6, l = tid & 63;
    const int lo = l & 15, hi = l >> 4;
    const int r0 = blockIdx.x * 16;
    const int c = w * 16 + lo;                 // this thread's gate column (w<13 always)
    const bool act = (c < 200);

    for (int i = tid; i < 16 * HSTRB; i += 832) hS[i] = 0;
    __syncthreads();

    float bh0 = 0.f, bh1 = 0.f, bh2 = 0.f;
    if (act) { bh0 = b_hh[c]; bh1 = b_hh[200 + c]; bh2 = b_hh[400 + c]; }
    float h_reg[4] = {0.f, 0.f, 0.f, 0.f};     // fp32 h for rows hi*4+r at col c

    for (int t = 0; t < 50; ++t) {
        // GI gate inputs for this step (independent; issue early)
        float gi_r[4], gi_z[4], gi_n[4];
        if (act) {
#pragma unroll
            for (int r = 0; r < 4; ++r) {
                const size_t gib = (size_t)((r0 + hi * 4 + r) * 50 + t) * 800;
                gi_r[r] = bf2f(GI[gib + c]);
                gi_z[r] = bf2f(GI[gib + 200 + c]);
                gi_n[r] = bf2f(GI[gib + 400 + c]);
            }
        }
        // A-fragments of h (bf16 direct)
        bf16x8 hf[7];
#pragma unroll
        for (int kk = 0; kk < 7; ++kk)
            hf[kk] = __builtin_bit_cast(bf16x8,
                *(const short8*)&hS[lo * HSTRB + kk * 32 + hi * 8]);

        // gh = h @ W_hh : 3 gates x 1 s-tile per wave
        f32x4 acc[3];
#pragma unroll
        for (int g = 0; g < 3; ++g) acc[g] = f32x4{0.f, 0.f, 0.f, 0.f};
#pragma unroll
        for (int g = 0; g < 3; ++g) {
            const int nt = g * 13 + w;
#pragma unroll
            for (int kk = 0; kk < 7; ++kk) {
                bf16x8 b = __builtin_bit_cast(bf16x8,
                    *(const short8*)&Whh_p[((kk * 39 + nt) * 64 + l) * 8]);
                acc[g] = __builtin_amdgcn_mfma_f32_16x16x32_bf16(hf[kk], b, acc[g], 0, 0, 0);
            }
        }

        float hnew[4];
        if (act) {
#pragma unroll
            for (int r = 0; r < 4; ++r) {
                const float gr = gi_r[r] + acc[0][r] + bh0;
                const float gz = gi_z[r] + acc[1][r] + bh1;
                const float hn = acc[2][r] + bh2;
                const float rr = 1.f / (1.f + __expf(-gr));
                const float zz = 1.f / (1.f + __expf(-gz));
                const float nn = tanhf(gi_n[r] + rr * hn);
                hnew[r] = (1.f - zz) * nn + zz * h_reg[r];
            }
        }
        __syncthreads();                       // B1: all hS reads of step t done
        if (act) {
#pragma unroll
            for (int r = 0; r < 4; ++r) {
                const int row = hi * 4 + r;
                const size_t bt = (size_t)((r0 + row) * 50 + t);
                h_reg[r] = hnew[r];
                hS[row * HSTRB + c] = f2bf(hnew[r]);
                out[bt * 350 + c] = hnew[r];               // deter fp32
                GI[bt * 800 + c]  = f2bf(hnew[r]);         // deter bf16 for k3
            }
        }
        __syncthreads();                       // B2: h' visible
    }
}

// ---------------- kernel 3: heads, fully parallel over 51200 rows ----------------
__global__ __launch_bounds__(256, 1) void k3_heads(
    const unsigned short* __restrict__ GI,     // deter bf16 cols 0..199, QE cols 600..799
    const unsigned short* __restrict__ Wpq1,
    const unsigned short* __restrict__ Wpq2,
    const float* __restrict__ noise,           // [51200][30]
    const float* __restrict__ bp1,
    const float* __restrict__ bp2,
    const float* __restrict__ bq2,
    float* __restrict__ out)                   // cols 200..349
{
    __shared__ unsigned short pq[2][16 * HSTRB];  // [0]=elu prior h1, [1]=elu post h1
    __shared__ float ost[16 * 128];               // pm|ps|qm|qs raw

    const int tid = threadIdx.x;
    const int w = tid >> 6, l = tid & 63;
    const int lo = l & 15, hi = l >> 4;
    const int r0 = blockIdx.x * 16;

    {   unsigned short* p0 = &pq[0][0];
        for (int i = tid; i < 2 * 16 * HSTRB; i += 256) p0[i] = 0; }
    __syncthreads();

    // A-fragments: deter from GI (K pad 200..223 garbage x B-zero = safe)
    bf16x8 af[7];
#pragma unroll
    for (int kk = 0; kk < 7; ++kk)
        af[kk] = __builtin_bit_cast(bf16x8,
            *(const short8*)&GI[(size_t)(r0 + lo) * 800 + kk * 32 + hi * 8]);

    // heads1: 26 N-tiles over 4 waves (7/7/6/6)
    const int h1s = (w < 2) ? 7 * w : 14 + 6 * (w - 2);
    const int h1n = (w < 2) ? 7 : 6;
    f32x4 a2[7];
#pragma unroll
    for (int i = 0; i < 7; ++i) a2[i] = f32x4{0.f, 0.f, 0.f, 0.f};
#pragma unroll
    for (int i = 0; i < 7; ++i) if (i < h1n) {
        const int nt = h1s + i;
#pragma unroll
        for (int kk = 0; kk < 7; ++kk) {
            bf16x8 b = __builtin_bit_cast(bf16x8,
                *(const short8*)&Wpq1[((kk * 26 + nt) * 64 + l) * 8]);
            a2[i] = __builtin_amdgcn_mfma_f32_16x16x32_bf16(af[kk], b, a2[i], 0, 0, 0);
        }
    }
#pragma unroll
    for (int i = 0; i < 7; ++i) if (i < h1n) {
        const int nt = h1s + i;
        const bool isq = (nt >= 13);
        const int c1 = (isq ? (nt - 13) : nt) * 16 + lo;
        if (c1 < 200) {
#pragma unroll
            for (int r = 0; r < 4; ++r) {
                const int row = hi * 4 + r;
                float v = a2[i][r];
                if (isq) v += bf2f(GI[(size_t)(r0 + row) * 800 + 600 + c1]);  // QE (incl bq1)
                else     v += bp1[c1];
                v = (v > 0.f) ? v : expm1f(v);                                 // ELU
                pq[isq ? 1 : 0][row * HSTRB + c1] = f2bf(v);
            }
        }
    }
    __syncthreads();

    // heads2: waves 0,1 -> prior (tiles 0..3); waves 2,3 -> posterior (tiles 4..7)
    const unsigned short* srcS = &pq[(w >= 2) ? 1 : 0][0];
    bf16x8 pf[7];
#pragma unroll
    for (int kk = 0; kk < 7; ++kk)
        pf[kk] = __builtin_bit_cast(bf16x8,
            *(const short8*)&srcS[lo * HSTRB + kk * 32 + hi * 8]);
    f32x4 a3[2];
    a3[0] = f32x4{0.f, 0.f, 0.f, 0.f};
    a3[1] = f32x4{0.f, 0.f, 0.f, 0.f};
#pragma unroll
    for (int i = 0; i < 2; ++i) {
        const int nt = ((w >= 2) ? 4 : 0) + (w & 1) * 2 + i;
#pragma unroll
        for (int kk = 0; kk < 7; ++kk) {
            bf16x8 b = __builtin_bit_cast(bf16x8,
                *(const short8*)&Wpq2[((kk * 8 + nt) * 64 + l) * 8]);
            a3[i] = __builtin_amdgcn_mfma_f32_16x16x32_bf16(pf[kk], b, a3[i], 0, 0, 0);
        }
    }
#pragma unroll
    for (int i = 0; i < 2; ++i) {
        const int nt = ((w >= 2) ? 4 : 0) + (w & 1) * 2 + i;
        const int cl = (nt & 3) * 16 + lo;
        if (cl < 60) {
            const float bb = (nt < 4) ? bp2[cl] : bq2[cl];
            const int obase = ((nt < 4) ? 0 : 64) + ((cl < 30) ? cl : (32 + cl - 30));
#pragma unroll
            for (int r = 0; r < 4; ++r)
                ost[(hi * 4 + r) * 128 + obase] = a3[i][r] + bb;
        }
    }
    __syncthreads();

    // pack cols 200..349
    for (int idx = tid; idx < 16 * 150; idx += 256) {
        const int row = idx / 150;
        const int c = 200 + (idx - row * 150);
        const size_t bt = (size_t)(r0 + row);
        const float* o = &ost[row * 128];
        float v;
        if (c < 230) {
            const int j = c - 200;
            const float qs = softplusf(o[96 + j]) + 0.1f;
            v = o[64 + j] + qs * noise[bt * 30 + j];
        }
        else if (c < 260) v = o[c - 230];
        else if (c < 290) v = softplusf(o[32 + (c - 260)]) + 0.1f;
        else if (c < 320) v = o[64 + (c - 290)];
        else              v = softplusf(o[96 + (c - 320)]) + 0.1f;
        out[bt * 350 + c] = v;
    }
}

// ---------------------------------------------------------------------------
extern "C" void kernel_launch(void* const* d_in, const int* in_sizes, int n_in,
                              void* d_out, int out_size, void* d_ws, size_t ws_size,
                              hipStream_t stream)
{
    const float* action = (const float*)d_in[0];
    const float* embed  = (const float*)d_in[1];
    const float* noise  = (const float*)d_in[2];
    const float* W_ih   = (const float*)d_in[3];
    const float* W_hh   = (const float*)d_in[4];
    const float* b_ih   = (const float*)d_in[5];
    const float* b_hh   = (const float*)d_in[6];
    const float* Wp1    = (const float*)d_in[7];
    const float* bp1    = (const float*)d_in[8];
    const float* Wp2    = (const float*)d_in[9];
    const float* bp2    = (const float*)d_in[10];
    const float* Wq1    = (const float*)d_in[11];
    const float* bq1    = (const float*)d_in[12];
    const float* Wq2    = (const float*)d_in[13];
    const float* bq2    = (const float*)d_in[14];
    (void)in_sizes; (void)n_in; (void)out_size; (void)ws_size;

    char* ws = (char*)d_ws;
    unsigned short* GI    = (unsigned short*)(ws);
    unsigned short* Bpack = (unsigned short*)(ws + OFF_BPACK);
    unsigned short* Whh_p = (unsigned short*)(ws + OFF_WHH);
    unsigned short* Wpq1  = (unsigned short*)(ws + OFF_WPQ1);
    unsigned short* Wpq2  = (unsigned short*)(ws + OFF_WPQ2);
    float* outp = (float*)d_out;

    pack_kernel<<<4222, 256, 0, stream>>>(W_ih, W_hh, Wp1, Wq1, Wp2, Wq2,
                                          Bpack, Whh_p, Wpq1, Wpq2);
    k1_gi<<<800, 512, 0, stream>>>(embed, action, W_ih, b_ih, bq1, Bpack, GI);
    k2_scan<<<64, 832, 0, stream>>>(GI, Whh_p, b_hh, outp);
    k3_heads<<<3200, 256, 0, stream>>>(GI, Wpq1, Wpq2, noise, bp1, bp2, bq2, outp);
}